// Round 20
// baseline (4907.918 us; speedup 1.0000x reference)
//
#include <hip/hip_runtime.h>
#include <math.h>

#define NN 512
#define BB 32
#define TT 12
#define HH 12
#define UU 64
#define CAP 128
#define RTOT (NN * BB)          // 16384 rows

__device__ __forceinline__ float sigm(float x) { return 1.f / (1.f + expf(-x)); }

__global__ void zero_kernel(float* __restrict__ p, int n) {
    int i = blockIdx.x * 256 + threadIdx.x;
    if (i < n) p[i] = 0.0f;
}

// ---------------- per-row nonzero counts (wave per row, both supports) ----------
__global__ __launch_bounds__(256) void row_counts(const float* __restrict__ sup,
                                                  int* __restrict__ cnt) {
    int wave = (blockIdx.x * 256 + threadIdx.x) >> 6;
    int lane = threadIdx.x & 63;
    if (wave >= 2 * NN) return;
    const float* row = sup + (size_t)wave * NN;
    int c = 0;
    for (int k = 0; k < 8; ++k)
        c += __popcll(__ballot(row[k * 64 + lane] != 0.0f));
    if (lane == 0) cnt[wave] = c;
}

// ---------------- degree-sort permutation (deterministic counting sort) ---------
__global__ __launch_bounds__(512) void perm_build(const int* __restrict__ cnt,
                                                  int* __restrict__ nmap,
                                                  int* __restrict__ rankv) {
    __shared__ int hist[520];
    __shared__ int keys[512];
    int n = threadIdx.x;
    int c0 = cnt[n], c1 = cnt[NN + n];
    int key = c0 > c1 ? c0 : c1;
    hist[n] = 0;
    if (n < 8) hist[512 + n] = 0;
    __syncthreads();
    keys[n] = key;
    atomicAdd(&hist[key], 1);
    __syncthreads();
    if (n == 0) {
        int s = 0;
        for (int i = 0; i < 520; ++i) { int h = hist[i]; hist[i] = s; s += h; }
    }
    __syncthreads();
    int pos = hist[key];
    for (int i = 0; i < n; ++i)
        if (keys[i] == key) ++pos;
    nmap[pos] = n;
    rankv[n] = pos;
}

// ---------------- ELL build in permuted node space, pre-baked LDS offsets -------
__global__ __launch_bounds__(256) void build_ell(const float* __restrict__ sup,
                                                 const int* __restrict__ nmap,
                                                 const int* __restrict__ rankv,
                                                 int2* __restrict__ ell8,
                                                 int2* __restrict__ ell4,
                                                 int* __restrict__ ecnt) {
    int wave = (blockIdx.x * blockDim.x + threadIdx.x) >> 6;
    int lane = threadIdx.x & 63;
    if (wave >= 2 * NN) return;
    int s = wave >> 9, rp = wave & 511;
    const float* row = sup + ((size_t)s * NN + nmap[rp]) * NN;
    int base = 0;
    for (int k = 0; k < NN / 64; ++k) {
        float v = row[k * 64 + lane];
        unsigned long long m = __ballot(v != 0.0f);
        int pre = __popcll(m & ((1ull << lane) - 1ull));
        if (v != 0.0f) {
            int pos = base + pre;
            if (pos < CAP) {
                int j = rankv[k * 64 + lane];
                int vb = __float_as_int(v);
                ell8[(size_t)pos * 1024 + wave] = make_int2(j * 32 + ((j >> 2) & 1) * 16, vb);
                ell4[(size_t)pos * 1024 + wave] = make_int2(j * 16, vb);
            }
        }
        base += __popcll(m);
    }
    if (lane == 0) ecnt[wave] = base < CAP ? base : CAP;
}

__global__ void wmax_kernel(const int* __restrict__ ecnt, int* __restrict__ wmax) {
    int g = threadIdx.x;
    if (g >= 16) return;
    int s = g >> 3, grp = g & 7;
    int m = 0;
    for (int i = 0; i < 64; ++i) {
        int c = ecnt[s * NN + grp * 64 + i];
        m = c > m ? c : m;
    }
    wmax[g] = m;
}

// ---------------- weight prep: permute to [oq][m][c][WD] + x-row table ----------
__global__ void wprep(const float* __restrict__ src, float* __restrict__ dstP,
                      float* __restrict__ dstX, int C, int OO, int WD, int L0) {
    int idx = blockIdx.x * 256 + threadIdx.x;
    int total = 5 * C * OO;
    if (idx >= total) return;
    int oi = idx % WD;
    int rem = idx / WD;
    int c = rem % C;
    int rem2 = rem / C;
    int m = rem2 % 5;
    int oq = rem2 / 5;
    int o = oq * WD + oi;
    int crow = L0 ? (c + 1) : c;
    size_t base = (size_t)crow * 5 * OO + o;
    float v;
    if (m == 0) v = src[base] - src[base + 2 * OO] - src[base + 4 * OO];
    else        v = src[base + (size_t)m * OO];
    dstP[idx] = v;
    if (L0 && c == 0) {
        size_t b0 = (size_t)o;
        float xvv;
        if (m == 0) xvv = src[b0] - src[b0 + 2 * OO] - src[b0 + 4 * OO];
        else        xvv = src[b0 + (size_t)m * OO];
        dstX[(oq * 5 + m) * WD + oi] = xvv;
    }
}

// ---------------- fused gconv body (device fn; byte-identical logic to R19) -----
template<bool L0, bool GATE>
__device__ __forceinline__ void fused_body(int bid, float* __restrict__ S,
                                           const float* __restrict__ hA,
                                           const float* __restrict__ hB,
                                           const float* __restrict__ g,
                                           const float* __restrict__ Wp,
                                           const float* __restrict__ Xr,
                                           const float* __restrict__ xv,
                                           const int* __restrict__ nmap,
                                           const float* __restrict__ bias,
                                           const int2* __restrict__ ell,
                                           const int* __restrict__ wmax,
                                           float* __restrict__ gout,
                                           const float* __restrict__ hOld,
                                           float* __restrict__ hNew) {
    constexpr int C  = L0 ? 64 : 128;
    constexpr int WD = GATE ? 8 : 4;

    float* T0 = S;
    float* T1 = S + 512 * WD;

    int swz = (bid & 7) * 64 + (bid >> 3);  // XCD-contiguous (512 sub-blocks)
    int b = swz >> 4, oq = swz & 15;
    int o0 = oq * WD;
    int n = threadIdx.x;
    int wm0 = wmax[n >> 6];
    int wm1 = wmax[8 + (n >> 6)];
    float xn = L0 ? xv[b * 512 + nmap[n]] : 0.f;

    const float* Wb = Wp + (size_t)oq * 5 * C * WD;
    float acc[5][WD];
    #pragma unroll
    for (int oi = 0; oi < WD; ++oi) acc[0][oi] = bias[o0 + oi];
    #pragma unroll
    for (int m = 1; m < 5; ++m)
        #pragma unroll
        for (int oi = 0; oi < WD; ++oi) acc[m][oi] = 0.f;

    #pragma unroll 2
    for (int c = 0; c < C; ++c) {
        float a;
        if (L0) {
            if (GATE) a = hA[(size_t)((b << 6) + c) * 512 + n];
            else      a = g[(size_t)((b << 7) + c) * 512 + n];          // rh
        } else {
            if (c < 64) {
                a = hA[(size_t)((b << 6) + c) * 512 + n];
            } else {
                int u = c - 64;
                if (GATE) a = hB[(size_t)((b << 6) + u) * 512 + n];
                else      a = g[(size_t)((b << 7) + u) * 512 + n];      // rh
            }
        }
        #pragma unroll
        for (int m = 0; m < 5; ++m) {
            const float* wrow = Wb + ((size_t)m * C + c) * WD;
            #pragma unroll
            for (int oi = 0; oi < WD; ++oi)
                acc[m][oi] += a * wrow[oi];
        }
    }

    if (L0) {
        const float* xr = Xr + (size_t)oq * 5 * WD;
        #pragma unroll
        for (int m = 0; m < 5; ++m)
            #pragma unroll
            for (int oi = 0; oi < WD; ++oi)
                acc[m][oi] += xn * xr[m * WD + oi];
    }

    float uval[WD], hval[WD];
    if (!GATE) {
        #pragma unroll
        for (int oi = 0; oi < WD; ++oi) {
            uval[oi] = g[(size_t)((b << 7) + 64 + o0 + oi) * 512 + n];
            hval[oi] = hOld[(size_t)((b << 6) + o0 + oi) * 512 + n];
        }
    }

    int hsel = (n >> 2) & 1;
    if constexpr (WD == 8) {
        *(float4*)&T0[n * 8 + hsel * 4] =
            make_float4(acc[2][0], acc[2][1], acc[2][2], acc[2][3]);
        *(float4*)&T0[n * 8 + (hsel ^ 1) * 4] =
            make_float4(acc[2][4], acc[2][5], acc[2][6], acc[2][7]);
        *(float4*)&T1[n * 8 + hsel * 4] =
            make_float4(acc[4][0], acc[4][1], acc[4][2], acc[4][3]);
        *(float4*)&T1[n * 8 + (hsel ^ 1) * 4] =
            make_float4(acc[4][4], acc[4][5], acc[4][6], acc[4][7]);
    } else {
        *(float4*)&T0[n * 4] = make_float4(acc[2][0], acc[2][1], acc[2][2], acc[2][3]);
        *(float4*)&T1[n * 4] = make_float4(acc[4][0], acc[4][1], acc[4][2], acc[4][3]);
    }

    auto gather = [&](const float* T, const int2* e0, int wm, float* o) {
        const char* Tbyte = (const char*)T;
        float a0[WD];
        #pragma unroll
        for (int i = 0; i < WD; ++i) a0[i] = 0.f;
        #pragma unroll 2
        for (int p = 0; p < wm; ++p) {
            int2 e = e0[(size_t)p << 10];
            float v = __int_as_float(e.y);
            if constexpr (WD == 8) {
                float4 x0 = *(const float4*)(Tbyte + e.x);
                float4 x1 = *(const float4*)(Tbyte + (e.x ^ 16));
                a0[0] += v * x0.x; a0[1] += v * x0.y; a0[2] += v * x0.z; a0[3] += v * x0.w;
                a0[4] += v * x1.x; a0[5] += v * x1.y; a0[6] += v * x1.z; a0[7] += v * x1.w;
            } else {
                float4 x0 = *(const float4*)(Tbyte + e.x);
                a0[0] += v * x0.x; a0[1] += v * x0.y; a0[2] += v * x0.z; a0[3] += v * x0.w;
            }
        }
        #pragma unroll
        for (int i = 0; i < WD; ++i) o[i] = a0[i];
    };
    auto put = [&](float* T, const float* y) {
        if constexpr (WD == 8) {
            *(float4*)&T[n * 8 + hsel * 4]       = make_float4(y[0], y[1], y[2], y[3]);
            *(float4*)&T[n * 8 + (hsel ^ 1) * 4] = make_float4(y[4], y[5], y[6], y[7]);
        } else {
            *(float4*)&T[n * 4] = make_float4(y[0], y[1], y[2], y[3]);
        }
    };

    const int2* e00 = ell + n;
    const int2* e01 = ell + NN + n;
    float g2[WD], g4[WD], t1[WD];

    __syncthreads();                    // bar 1: T0/T1 staged

    gather(T0, e00, wm0, t1);           // S1 Z2
    #pragma unroll
    for (int oi = 0; oi < WD; ++oi) acc[1][oi] += 2.f * t1[oi];
    gather(T1, e01, wm1, t1);           // S2 Z4
    #pragma unroll
    for (int oi = 0; oi < WD; ++oi) acc[3][oi] += 2.f * t1[oi];

    __syncthreads();                    // bar 2: hop-1 reads done

    put(T0, acc[1]);
    put(T1, acc[3]);

    __syncthreads();                    // bar 3: y tiles ready

    gather(T0, e00, wm0, g2);           // S1 y1
    gather(T1, e01, wm1, g4);           // S2 y2

    #pragma unroll
    for (int oi = 0; oi < WD; ++oi) {
        float accf = acc[0][oi] + g2[oi] + g4[oi];
        if (GATE) {
            float s = sigm(accf);
            if (oq < 8) {               // r-half: write rh = r * h (rh-fusion)
                const float* hG = L0 ? hA : hB;
                float hv = hG[(size_t)((b << 6) + o0 + oi) * 512 + n];
                gout[(size_t)((b << 7) + o0 + oi) * 512 + n] = s * hv;
            } else {
                gout[(size_t)((b << 7) + o0 + oi) * 512 + n] = s;
            }
        } else {
            float cv = tanhf(accf);
            hNew[(size_t)((b << 6) + o0 + oi) * 512 + n] =
                uval[oi] * hval[oi] + (1.f - uval[oi]) * cv;
        }
    }
}

// ---------------- standalone kernel ---------------------------------------------
template<bool L0, bool GATE>
__global__ __launch_bounds__(512) void fused(const float* __restrict__ hA,
                                             const float* __restrict__ hB,
                                             const float* __restrict__ g,
                                             const float* __restrict__ Wp,
                                             const float* __restrict__ Xr,
                                             const float* __restrict__ xv,
                                             const int* __restrict__ nmap,
                                             const float* __restrict__ bias,
                                             const int2* __restrict__ ell,
                                             const int* __restrict__ wmax,
                                             float* __restrict__ gout,
                                             const float* __restrict__ hOld,
                                             float* __restrict__ hNew) {
    __shared__ float S[512 * (GATE ? 8 : 4) * 2];
    fused_body<L0, GATE>(blockIdx.x, S, hA, hB, g, Wp, Xr, xv, nmap, bias,
                         ell, wmax, gout, hOld, hNew);
}

// ---------------- paired kernel: even bids = l1-type cell, odd = l0-type --------
template<bool GATE>
__global__ __launch_bounds__(512) void fused_pair(
        const int* __restrict__ nmap, const int2* __restrict__ ell,
        const int* __restrict__ wmax,
        // unit A (L0=false)
        const float* __restrict__ AhA, const float* __restrict__ AhB,
        const float* __restrict__ Ag,  const float* __restrict__ AWp,
        const float* __restrict__ Abias, float* __restrict__ Agout,
        const float* __restrict__ AhOld, float* __restrict__ AhNew,
        // unit B (L0=true)
        const float* __restrict__ BhA, const float* __restrict__ Bg,
        const float* __restrict__ BWp, const float* __restrict__ BXr,
        const float* __restrict__ Bxv, const float* __restrict__ Bbias,
        float* __restrict__ Bgout, const float* __restrict__ BhOld,
        float* __restrict__ BhNew) {
    __shared__ float S[512 * (GATE ? 8 : 4) * 2];
    int unit = blockIdx.x & 1, sub = blockIdx.x >> 1;
    if (unit == 0)
        fused_body<false, GATE>(sub, S, AhA, AhB, Ag, AWp, nullptr, nullptr,
                                nmap, Abias, ell, wmax, Agout, AhOld, AhNew);
    else
        fused_body<true, GATE>(sub, S, BhA, nullptr, Bg, BWp, BXr, Bxv,
                               nmap, Bbias, ell, wmax, Bgout, BhOld, BhNew);
}

// ---------------- projection (write through nmap to original node order) --------
__global__ void proj_kernel(const float* __restrict__ h1, const float* __restrict__ pW,
                            const float* __restrict__ pb, const int* __restrict__ nmap,
                            float* __restrict__ outt) {
    int r = blockIdx.x * 256 + threadIdx.x;
    if (r >= RTOT) return;
    int b = r >> 9, n = r & 511;
    float acc = pb[0];
    #pragma unroll 16
    for (int u = 0; u < 64; ++u)
        acc += h1[(size_t)((b << 6) + u) * 512 + n] * pW[u];
    outt[b * NN + nmap[n]] = acc;
}

// ================================================================================
extern "C" void kernel_launch(void* const* d_in, const int* in_sizes, int n_in,
                              void* d_out, int out_size, void* d_ws, size_t ws_size,
                              hipStream_t stream) {
    const float* inputs   = (const float*)d_in[0];
    const float* supports = (const float*)d_in[1];
    const float* enc0_Wg = (const float*)d_in[2];
    const float* enc0_bg = (const float*)d_in[3];
    const float* enc0_Wc = (const float*)d_in[4];
    const float* enc0_bc = (const float*)d_in[5];
    const float* enc1_Wg = (const float*)d_in[6];
    const float* enc1_bg = (const float*)d_in[7];
    const float* enc1_Wc = (const float*)d_in[8];
    const float* enc1_bc = (const float*)d_in[9];
    const float* dec0_Wg = (const float*)d_in[10];
    const float* dec0_bg = (const float*)d_in[11];
    const float* dec0_Wc = (const float*)d_in[12];
    const float* dec0_bc = (const float*)d_in[13];
    const float* dec1_Wg = (const float*)d_in[14];
    const float* dec1_bg = (const float*)d_in[15];
    const float* dec1_Wc = (const float*)d_in[16];
    const float* dec1_bc = (const float*)d_in[17];
    const float* projW   = (const float*)d_in[18];
    const float* projb   = (const float*)d_in[19];
    float* out = (float*)d_out;

    char* wsb = (char*)d_ws;
    size_t off = 0;
    auto alloc = [&](size_t bytes) -> char* {
        char* p = wsb + off;
        off = (off + bytes + 255) & ~(size_t)255;
        return p;
    };
    int2*  ell8  = (int2*)alloc((size_t)CAP * 1024 * 8);
    int2*  ell4  = (int2*)alloc((size_t)CAP * 1024 * 8);
    int*   cnt   = (int*)alloc((size_t)2 * NN * 4);
    int*   nmap  = (int*)alloc((size_t)NN * 4);
    int*   rankv = (int*)alloc((size_t)NN * 4);
    int*   ecnt  = (int*)alloc((size_t)2 * NN * 4);
    int*   wmax  = (int*)alloc((size_t)16 * 4);
    float* h0a   = (float*)alloc((size_t)RTOT * UU * 4);     // [b][u][n]
    float* h1a   = (float*)alloc((size_t)RTOT * UU * 4);
    float* xzero = (float*)alloc((size_t)RTOT * 4);
    float* h0b   = (float*)alloc((size_t)RTOT * UU * 4);
    float* h1b   = (float*)alloc((size_t)RTOT * UU * 4);
    float* g0    = (float*)alloc((size_t)RTOT * 128 * 4);
    float* g1    = (float*)alloc((size_t)RTOT * 128 * 4);
    float* p_e0g = (float*)alloc((size_t)5 * 64 * 128 * 4);
    float* x_e0g = (float*)alloc((size_t)16 * 5 * 8 * 4);
    float* p_e0c = (float*)alloc((size_t)5 * 64 * 64 * 4);
    float* x_e0c = (float*)alloc((size_t)16 * 5 * 4 * 4);
    float* p_e1g = (float*)alloc((size_t)5 * 128 * 128 * 4);
    float* p_e1c = (float*)alloc((size_t)5 * 128 * 64 * 4);
    float* p_d0g = (float*)alloc((size_t)5 * 64 * 128 * 4);
    float* x_d0g = (float*)alloc((size_t)16 * 5 * 8 * 4);
    float* p_d0c = (float*)alloc((size_t)5 * 64 * 64 * 4);
    float* x_d0c = (float*)alloc((size_t)16 * 5 * 4 * 4);
    float* p_d1g = (float*)alloc((size_t)5 * 128 * 128 * 4);
    float* p_d1c = (float*)alloc((size_t)5 * 128 * 64 * 4);
    float* xdum  = (float*)alloc((size_t)16 * 5 * 8 * 4);
    if (off > ws_size) return;

    {
        int nz = CAP * 1024 * 4;  // ell8 + ell4 as ints (contiguous)
        zero_kernel<<<(nz + 255) / 256, 256, 0, stream>>>((float*)ell8, nz);
    }
    row_counts<<<256, 256, 0, stream>>>(supports, cnt);
    perm_build<<<1, 512, 0, stream>>>(cnt, nmap, rankv);
    build_ell<<<256, 256, 0, stream>>>(supports, nmap, rankv, ell8, ell4, ecnt);
    wmax_kernel<<<1, 16, 0, stream>>>(ecnt, wmax);
    {
        int nz = RTOT * UU * 2 + RTOT;  // h0a, h1a, xzero contiguous
        zero_kernel<<<(nz + 255) / 256, 256, 0, stream>>>(h0a, nz);
    }
    wprep<<<(5 * 64 * 128 + 255) / 256, 256, 0, stream>>>(enc0_Wg, p_e0g, x_e0g, 64, 128, 8, 1);
    wprep<<<(5 * 64 * 64 + 255) / 256, 256, 0, stream>>>(enc0_Wc, p_e0c, x_e0c, 64, 64, 4, 1);
    wprep<<<(5 * 128 * 128 + 255) / 256, 256, 0, stream>>>(enc1_Wg, p_e1g, xdum, 128, 128, 8, 0);
    wprep<<<(5 * 128 * 64 + 255) / 256, 256, 0, stream>>>(enc1_Wc, p_e1c, xdum, 128, 64, 4, 0);
    wprep<<<(5 * 64 * 128 + 255) / 256, 256, 0, stream>>>(dec0_Wg, p_d0g, x_d0g, 64, 128, 8, 1);
    wprep<<<(5 * 64 * 64 + 255) / 256, 256, 0, stream>>>(dec0_Wc, p_d0c, x_d0c, 64, 64, 4, 1);
    wprep<<<(5 * 128 * 128 + 255) / 256, 256, 0, stream>>>(dec1_Wg, p_d1g, xdum, 128, 128, 8, 0);
    wprep<<<(5 * 128 * 64 + 255) / 256, 256, 0, stream>>>(dec1_Wc, p_d1c, xdum, 128, 64, 4, 0);

    float *h0c = h0a, *h0n = h0b, *h1c = h1a, *h1n = h1b;

    auto cell_l0 = [&](const float* x_bn, const float* Wg_, const float* Xg_,
                       const float* bg_, const float* Wc_, const float* Xc_,
                       const float* bc_) {
        fused<true, true><<<512, 512, 0, stream>>>(h0c, nullptr, g0, Wg_, Xg_, x_bn, nmap,
                                                   bg_, ell8, wmax, g0, nullptr, nullptr);
        fused<true, false><<<512, 512, 0, stream>>>(h0c, nullptr, g0, Wc_, Xc_, x_bn, nmap,
                                                    bc_, ell4, wmax, nullptr, h0c, h0n);
        float* t = h0c; h0c = h0n; h0n = t;
    };
    auto cell_l1 = [&](const float* Wg_, const float* bg_,
                       const float* Wc_, const float* bc_) {
        fused<false, true><<<512, 512, 0, stream>>>(h0c, h1c, g1, Wg_, nullptr, nullptr, nmap,
                                                    bg_, ell8, wmax, g1, nullptr, nullptr);
        fused<false, false><<<512, 512, 0, stream>>>(h0c, h1c, g1, Wc_, nullptr, nullptr, nmap,
                                                     bc_, ell4, wmax, nullptr, h1c, h1n);
        float* t = h1c; h1c = h1n; h1n = t;
    };
    // paired: A = enc l1 (uses h0c,h1c -> h1n), B = l0-type cell (xB, weights) -> h0n
    auto pair_step = [&](const float* xB, const float* BWg, const float* BXg,
                         const float* Bbg, const float* BWc, const float* BXc,
                         const float* Bbc) {
        fused_pair<true><<<1024, 512, 0, stream>>>(
            nmap, ell8, wmax,
            h0c, h1c, g1, p_e1g, enc1_bg, g1, nullptr, nullptr,
            h0c, g0, BWg, BXg, xB, Bbg, g0, nullptr, nullptr);
        fused_pair<false><<<1024, 512, 0, stream>>>(
            nmap, ell4, wmax,
            h0c, h1c, g1, p_e1c, enc1_bc, nullptr, h1c, h1n,
            h0c, g0, BWc, BXc, xB, Bbc, nullptr, h0c, h0n);
        float* t = h0c; h0c = h0n; h0n = t;
        t = h1c; h1c = h1n; h1n = t;
    };

    // ---- encoder with cross-cell pairing ----
    cell_l0(inputs, p_e0g, x_e0g, enc0_bg, p_e0c, x_e0c, enc0_bc);      // l0(0)
    for (int t = 1; t < TT; ++t)                                        // {l1(t-1) || l0(t)}
        pair_step(inputs + (size_t)t * BB * NN,
                  p_e0g, x_e0g, enc0_bg, p_e0c, x_e0c, enc0_bc);
    // bridge: {enc l1(11) || dec l0(0) with x = 0}
    pair_step(xzero, p_d0g, x_d0g, dec0_bg, p_d0c, x_d0c, dec0_bc);

    // ---- decoder (serial: out(t) feeds l0(t+1)) ----
    auto cell_l1_dec = [&]() {
        fused<false, true><<<512, 512, 0, stream>>>(h0c, h1c, g1, p_d1g, nullptr, nullptr, nmap,
                                                    dec1_bg, ell8, wmax, g1, nullptr, nullptr);
        fused<false, false><<<512, 512, 0, stream>>>(h0c, h1c, g1, p_d1c, nullptr, nullptr, nmap,
                                                     dec1_bc, ell4, wmax, nullptr, h1c, h1n);
        float* t = h1c; h1c = h1n; h1n = t;
    };

    cell_l1_dec();
    proj_kernel<<<(RTOT + 255) / 256, 256, 0, stream>>>(h1c, projW, projb, nmap, out);
    for (int t = 1; t < HH; ++t) {
        const float* xin = out + (size_t)(t - 1) * BB * NN;
        cell_l0(xin, p_d0g, x_d0g, dec0_bg, p_d0c, x_d0c, dec0_bc);
        cell_l1_dec();
        proj_kernel<<<(RTOT + 255) / 256, 256, 0, stream>>>(h1c, projW, projb, nmap,
                                                            out + (size_t)t * BB * NN);
    }
}

// Round 21
// 4633.788 us; speedup vs baseline: 1.0592x; 1.0592x over previous
//
#include <hip/hip_runtime.h>
#include <math.h>

#define NN 512
#define BB 32
#define TT 12
#define HH 12
#define UU 64
#define CAP 128
#define RTOT (NN * BB)          // 16384 rows

__device__ __forceinline__ float sigm(float x) { return 1.f / (1.f + expf(-x)); }

__global__ void zero_kernel(float* __restrict__ p, int n) {
    int i = blockIdx.x * 256 + threadIdx.x;
    if (i < n) p[i] = 0.0f;
}

// ---------------- per-row nonzero counts (wave per row, both supports) ----------
__global__ __launch_bounds__(256) void row_counts(const float* __restrict__ sup,
                                                  int* __restrict__ cnt) {
    int wave = (blockIdx.x * 256 + threadIdx.x) >> 6;
    int lane = threadIdx.x & 63;
    if (wave >= 2 * NN) return;
    const float* row = sup + (size_t)wave * NN;
    int c = 0;
    for (int k = 0; k < 8; ++k)
        c += __popcll(__ballot(row[k * 64 + lane] != 0.0f));
    if (lane == 0) cnt[wave] = c;
}

// ---------------- degree-sort permutation (deterministic counting sort) ---------
__global__ __launch_bounds__(512) void perm_build(const int* __restrict__ cnt,
                                                  int* __restrict__ nmap,
                                                  int* __restrict__ rankv) {
    __shared__ int hist[520];
    __shared__ int keys[512];
    int n = threadIdx.x;
    int c0 = cnt[n], c1 = cnt[NN + n];
    int key = c0 > c1 ? c0 : c1;
    hist[n] = 0;
    if (n < 8) hist[512 + n] = 0;
    __syncthreads();
    keys[n] = key;
    atomicAdd(&hist[key], 1);
    __syncthreads();
    if (n == 0) {
        int s = 0;
        for (int i = 0; i < 520; ++i) { int h = hist[i]; hist[i] = s; s += h; }
    }
    __syncthreads();
    int pos = hist[key];
    for (int i = 0; i < n; ++i)
        if (keys[i] == key) ++pos;
    nmap[pos] = n;
    rankv[n] = pos;
}

// ---------------- ELL build in permuted node space, pre-baked LDS offsets -------
__global__ __launch_bounds__(256) void build_ell(const float* __restrict__ sup,
                                                 const int* __restrict__ nmap,
                                                 const int* __restrict__ rankv,
                                                 int2* __restrict__ ell8,
                                                 int2* __restrict__ ell4,
                                                 int* __restrict__ ecnt) {
    int wave = (blockIdx.x * blockDim.x + threadIdx.x) >> 6;
    int lane = threadIdx.x & 63;
    if (wave >= 2 * NN) return;
    int s = wave >> 9, rp = wave & 511;
    const float* row = sup + ((size_t)s * NN + nmap[rp]) * NN;
    int base = 0;
    for (int k = 0; k < NN / 64; ++k) {
        float v = row[k * 64 + lane];
        unsigned long long m = __ballot(v != 0.0f);
        int pre = __popcll(m & ((1ull << lane) - 1ull));
        if (v != 0.0f) {
            int pos = base + pre;
            if (pos < CAP) {
                int j = rankv[k * 64 + lane];
                int vb = __float_as_int(v);
                ell8[(size_t)pos * 1024 + wave] = make_int2(j * 32 + ((j >> 2) & 1) * 16, vb);
                ell4[(size_t)pos * 1024 + wave] = make_int2(j * 16, vb);
            }
        }
        base += __popcll(m);
    }
    if (lane == 0) ecnt[wave] = base < CAP ? base : CAP;
}

__global__ void wmax_kernel(const int* __restrict__ ecnt, int* __restrict__ wmax) {
    int g = threadIdx.x;
    if (g >= 16) return;
    int s = g >> 3, grp = g & 7;
    int m = 0;
    for (int i = 0; i < 64; ++i) {
        int c = ecnt[s * NN + grp * 64 + i];
        m = c > m ? c : m;
    }
    wmax[g] = m;
}

// ---------------- weight prep: permute to [oq][m][c][WD] + x-row table ----------
__global__ void wprep(const float* __restrict__ src, float* __restrict__ dstP,
                      float* __restrict__ dstX, int C, int OO, int WD, int L0) {
    int idx = blockIdx.x * 256 + threadIdx.x;
    int total = 5 * C * OO;
    if (idx >= total) return;
    int oi = idx % WD;
    int rem = idx / WD;
    int c = rem % C;
    int rem2 = rem / C;
    int m = rem2 % 5;
    int oq = rem2 / 5;
    int o = oq * WD + oi;
    int crow = L0 ? (c + 1) : c;
    size_t base = (size_t)crow * 5 * OO + o;
    float v;
    if (m == 0) v = src[base] - src[base + 2 * OO] - src[base + 4 * OO];
    else        v = src[base + (size_t)m * OO];
    dstP[idx] = v;
    if (L0 && c == 0) {
        size_t b0 = (size_t)o;
        float xvv;
        if (m == 0) xvv = src[b0] - src[b0 + 2 * OO] - src[b0 + 4 * OO];
        else        xvv = src[b0 + (size_t)m * OO];
        dstX[(oq * 5 + m) * WD + oi] = xvv;
    }
}

// ---------------- fused gconv body (device fn; byte-identical logic to R19) -----
template<bool L0, bool GATE>
__device__ __forceinline__ void fused_body(int bid, float* __restrict__ S,
                                           const float* __restrict__ hA,
                                           const float* __restrict__ hB,
                                           const float* __restrict__ g,
                                           const float* __restrict__ Wp,
                                           const float* __restrict__ Xr,
                                           const float* __restrict__ xv,
                                           const int* __restrict__ nmap,
                                           const float* __restrict__ bias,
                                           const int2* __restrict__ ell,
                                           const int* __restrict__ wmax,
                                           float* __restrict__ gout,
                                           const float* __restrict__ hOld,
                                           float* __restrict__ hNew) {
    constexpr int C  = L0 ? 64 : 128;
    constexpr int WD = GATE ? 8 : 4;

    float* T0 = S;
    float* T1 = S + 512 * WD;

    int swz = (bid & 7) * 64 + (bid >> 3);  // XCD-contiguous (512 sub-blocks)
    int b = swz >> 4, oq = swz & 15;
    int o0 = oq * WD;
    int n = threadIdx.x;
    int wm0 = wmax[n >> 6];
    int wm1 = wmax[8 + (n >> 6)];
    float xn = L0 ? xv[b * 512 + nmap[n]] : 0.f;

    const float* Wb = Wp + (size_t)oq * 5 * C * WD;
    float acc[5][WD];
    #pragma unroll
    for (int oi = 0; oi < WD; ++oi) acc[0][oi] = bias[o0 + oi];
    #pragma unroll
    for (int m = 1; m < 5; ++m)
        #pragma unroll
        for (int oi = 0; oi < WD; ++oi) acc[m][oi] = 0.f;

    #pragma unroll 2
    for (int c = 0; c < C; ++c) {
        float a;
        if (L0) {
            if (GATE) a = hA[(size_t)((b << 6) + c) * 512 + n];
            else      a = g[(size_t)((b << 7) + c) * 512 + n];          // rh
        } else {
            if (c < 64) {
                a = hA[(size_t)((b << 6) + c) * 512 + n];
            } else {
                int u = c - 64;
                if (GATE) a = hB[(size_t)((b << 6) + u) * 512 + n];
                else      a = g[(size_t)((b << 7) + u) * 512 + n];      // rh
            }
        }
        #pragma unroll
        for (int m = 0; m < 5; ++m) {
            const float* wrow = Wb + ((size_t)m * C + c) * WD;
            #pragma unroll
            for (int oi = 0; oi < WD; ++oi)
                acc[m][oi] += a * wrow[oi];
        }
    }

    if (L0) {
        const float* xr = Xr + (size_t)oq * 5 * WD;
        #pragma unroll
        for (int m = 0; m < 5; ++m)
            #pragma unroll
            for (int oi = 0; oi < WD; ++oi)
                acc[m][oi] += xn * xr[m * WD + oi];
    }

    float uval[WD], hval[WD];
    if (!GATE) {
        #pragma unroll
        for (int oi = 0; oi < WD; ++oi) {
            uval[oi] = g[(size_t)((b << 7) + 64 + o0 + oi) * 512 + n];
            hval[oi] = hOld[(size_t)((b << 6) + o0 + oi) * 512 + n];
        }
    }

    int hsel = (n >> 2) & 1;
    if constexpr (WD == 8) {
        *(float4*)&T0[n * 8 + hsel * 4] =
            make_float4(acc[2][0], acc[2][1], acc[2][2], acc[2][3]);
        *(float4*)&T0[n * 8 + (hsel ^ 1) * 4] =
            make_float4(acc[2][4], acc[2][5], acc[2][6], acc[2][7]);
        *(float4*)&T1[n * 8 + hsel * 4] =
            make_float4(acc[4][0], acc[4][1], acc[4][2], acc[4][3]);
        *(float4*)&T1[n * 8 + (hsel ^ 1) * 4] =
            make_float4(acc[4][4], acc[4][5], acc[4][6], acc[4][7]);
    } else {
        *(float4*)&T0[n * 4] = make_float4(acc[2][0], acc[2][1], acc[2][2], acc[2][3]);
        *(float4*)&T1[n * 4] = make_float4(acc[4][0], acc[4][1], acc[4][2], acc[4][3]);
    }

    auto gather = [&](const float* T, const int2* e0, int wm, float* o) {
        const char* Tbyte = (const char*)T;
        float a0[WD];
        #pragma unroll
        for (int i = 0; i < WD; ++i) a0[i] = 0.f;
        #pragma unroll 2
        for (int p = 0; p < wm; ++p) {
            int2 e = e0[(size_t)p << 10];
            float v = __int_as_float(e.y);
            if constexpr (WD == 8) {
                float4 x0 = *(const float4*)(Tbyte + e.x);
                float4 x1 = *(const float4*)(Tbyte + (e.x ^ 16));
                a0[0] += v * x0.x; a0[1] += v * x0.y; a0[2] += v * x0.z; a0[3] += v * x0.w;
                a0[4] += v * x1.x; a0[5] += v * x1.y; a0[6] += v * x1.z; a0[7] += v * x1.w;
            } else {
                float4 x0 = *(const float4*)(Tbyte + e.x);
                a0[0] += v * x0.x; a0[1] += v * x0.y; a0[2] += v * x0.z; a0[3] += v * x0.w;
            }
        }
        #pragma unroll
        for (int i = 0; i < WD; ++i) o[i] = a0[i];
    };
    auto put = [&](float* T, const float* y) {
        if constexpr (WD == 8) {
            *(float4*)&T[n * 8 + hsel * 4]       = make_float4(y[0], y[1], y[2], y[3]);
            *(float4*)&T[n * 8 + (hsel ^ 1) * 4] = make_float4(y[4], y[5], y[6], y[7]);
        } else {
            *(float4*)&T[n * 4] = make_float4(y[0], y[1], y[2], y[3]);
        }
    };

    const int2* e00 = ell + n;
    const int2* e01 = ell + NN + n;
    float g2[WD], g4[WD], t1[WD];

    __syncthreads();                    // bar 1: T0/T1 staged

    gather(T0, e00, wm0, t1);           // S1 Z2
    #pragma unroll
    for (int oi = 0; oi < WD; ++oi) acc[1][oi] += 2.f * t1[oi];
    gather(T1, e01, wm1, t1);           // S2 Z4
    #pragma unroll
    for (int oi = 0; oi < WD; ++oi) acc[3][oi] += 2.f * t1[oi];

    __syncthreads();                    // bar 2: hop-1 reads done

    put(T0, acc[1]);
    put(T1, acc[3]);

    __syncthreads();                    // bar 3: y tiles ready

    gather(T0, e00, wm0, g2);           // S1 y1
    gather(T1, e01, wm1, g4);           // S2 y2

    #pragma unroll
    for (int oi = 0; oi < WD; ++oi) {
        float accf = acc[0][oi] + g2[oi] + g4[oi];
        if (GATE) {
            float s = sigm(accf);
            if (oq < 8) {               // r-half: write rh = r * h (rh-fusion)
                const float* hG = L0 ? hA : hB;
                float hv = hG[(size_t)((b << 6) + o0 + oi) * 512 + n];
                gout[(size_t)((b << 7) + o0 + oi) * 512 + n] = s * hv;
            } else {
                gout[(size_t)((b << 7) + o0 + oi) * 512 + n] = s;
            }
        } else {
            float cv = tanhf(accf);
            hNew[(size_t)((b << 6) + o0 + oi) * 512 + n] =
                uval[oi] * hval[oi] + (1.f - uval[oi]) * cv;
        }
    }
}

// ---------------- standalone kernel ---------------------------------------------
template<bool L0, bool GATE>
__global__ __launch_bounds__(512) void fused(const float* __restrict__ hA,
                                             const float* __restrict__ hB,
                                             const float* __restrict__ g,
                                             const float* __restrict__ Wp,
                                             const float* __restrict__ Xr,
                                             const float* __restrict__ xv,
                                             const int* __restrict__ nmap,
                                             const float* __restrict__ bias,
                                             const int2* __restrict__ ell,
                                             const int* __restrict__ wmax,
                                             float* __restrict__ gout,
                                             const float* __restrict__ hOld,
                                             float* __restrict__ hNew) {
    __shared__ float S[512 * (GATE ? 8 : 4) * 2];
    fused_body<L0, GATE>(blockIdx.x, S, hA, hB, g, Wp, Xr, xv, nmap, bias,
                         ell, wmax, gout, hOld, hNew);
}

// ---------------- paired kernel -------------------------------------------------
// CU co-residency fix: blocks sharing a CU are bid, bid+256, bid+512, bid+768
// (round-robin over 8 XCD x 32 CU = 256). unit = (bid>>8)&1 puts 2 A-blocks +
// 2 B-blocks on every CU -> VALU-phase of one type overlaps LDS-phase of other.
template<bool GATE>
__global__ __launch_bounds__(512) void fused_pair(
        const int* __restrict__ nmap, const int2* __restrict__ ell,
        const int* __restrict__ wmax,
        // unit A (L0=false)
        const float* __restrict__ AhA, const float* __restrict__ AhB,
        const float* __restrict__ Ag,  const float* __restrict__ AWp,
        const float* __restrict__ Abias, float* __restrict__ Agout,
        const float* __restrict__ AhOld, float* __restrict__ AhNew,
        // unit B (L0=true)
        const float* __restrict__ BhA, const float* __restrict__ Bg,
        const float* __restrict__ BWp, const float* __restrict__ BXr,
        const float* __restrict__ Bxv, const float* __restrict__ Bbias,
        float* __restrict__ Bgout, const float* __restrict__ BhOld,
        float* __restrict__ BhNew) {
    __shared__ float S[512 * (GATE ? 8 : 4) * 2];
    int chunk = blockIdx.x >> 8;                      // 0..3
    int unit = chunk & 1;
    int sub = ((chunk >> 1) << 8) + (blockIdx.x & 255);   // 0..511 per unit
    if (unit == 0)
        fused_body<false, GATE>(sub, S, AhA, AhB, Ag, AWp, nullptr, nullptr,
                                nmap, Abias, ell, wmax, Agout, AhOld, AhNew);
    else
        fused_body<true, GATE>(sub, S, BhA, nullptr, Bg, BWp, BXr, Bxv,
                               nmap, Bbias, ell, wmax, Bgout, BhOld, BhNew);
}

// ---------------- projection (write through nmap to original node order) --------
__global__ void proj_kernel(const float* __restrict__ h1, const float* __restrict__ pW,
                            const float* __restrict__ pb, const int* __restrict__ nmap,
                            float* __restrict__ outt) {
    int r = blockIdx.x * 256 + threadIdx.x;
    if (r >= RTOT) return;
    int b = r >> 9, n = r & 511;
    float acc = pb[0];
    #pragma unroll 16
    for (int u = 0; u < 64; ++u)
        acc += h1[(size_t)((b << 6) + u) * 512 + n] * pW[u];
    outt[b * NN + nmap[n]] = acc;
}

// ================================================================================
extern "C" void kernel_launch(void* const* d_in, const int* in_sizes, int n_in,
                              void* d_out, int out_size, void* d_ws, size_t ws_size,
                              hipStream_t stream) {
    const float* inputs   = (const float*)d_in[0];
    const float* supports = (const float*)d_in[1];
    const float* enc0_Wg = (const float*)d_in[2];
    const float* enc0_bg = (const float*)d_in[3];
    const float* enc0_Wc = (const float*)d_in[4];
    const float* enc0_bc = (const float*)d_in[5];
    const float* enc1_Wg = (const float*)d_in[6];
    const float* enc1_bg = (const float*)d_in[7];
    const float* enc1_Wc = (const float*)d_in[8];
    const float* enc1_bc = (const float*)d_in[9];
    const float* dec0_Wg = (const float*)d_in[10];
    const float* dec0_bg = (const float*)d_in[11];
    const float* dec0_Wc = (const float*)d_in[12];
    const float* dec0_bc = (const float*)d_in[13];
    const float* dec1_Wg = (const float*)d_in[14];
    const float* dec1_bg = (const float*)d_in[15];
    const float* dec1_Wc = (const float*)d_in[16];
    const float* dec1_bc = (const float*)d_in[17];
    const float* projW   = (const float*)d_in[18];
    const float* projb   = (const float*)d_in[19];
    float* out = (float*)d_out;

    char* wsb = (char*)d_ws;
    size_t off = 0;
    auto alloc = [&](size_t bytes) -> char* {
        char* p = wsb + off;
        off = (off + bytes + 255) & ~(size_t)255;
        return p;
    };
    int2*  ell8  = (int2*)alloc((size_t)CAP * 1024 * 8);
    int2*  ell4  = (int2*)alloc((size_t)CAP * 1024 * 8);
    int*   cnt   = (int*)alloc((size_t)2 * NN * 4);
    int*   nmap  = (int*)alloc((size_t)NN * 4);
    int*   rankv = (int*)alloc((size_t)NN * 4);
    int*   ecnt  = (int*)alloc((size_t)2 * NN * 4);
    int*   wmax  = (int*)alloc((size_t)16 * 4);
    float* h0a   = (float*)alloc((size_t)RTOT * UU * 4);     // [b][u][n]
    float* h1a   = (float*)alloc((size_t)RTOT * UU * 4);
    float* xzero = (float*)alloc((size_t)RTOT * 4);
    float* h0b   = (float*)alloc((size_t)RTOT * UU * 4);
    float* h1b   = (float*)alloc((size_t)RTOT * UU * 4);
    float* g0    = (float*)alloc((size_t)RTOT * 128 * 4);
    float* g1    = (float*)alloc((size_t)RTOT * 128 * 4);
    float* p_e0g = (float*)alloc((size_t)5 * 64 * 128 * 4);
    float* x_e0g = (float*)alloc((size_t)16 * 5 * 8 * 4);
    float* p_e0c = (float*)alloc((size_t)5 * 64 * 64 * 4);
    float* x_e0c = (float*)alloc((size_t)16 * 5 * 4 * 4);
    float* p_e1g = (float*)alloc((size_t)5 * 128 * 128 * 4);
    float* p_e1c = (float*)alloc((size_t)5 * 128 * 64 * 4);
    float* p_d0g = (float*)alloc((size_t)5 * 64 * 128 * 4);
    float* x_d0g = (float*)alloc((size_t)16 * 5 * 8 * 4);
    float* p_d0c = (float*)alloc((size_t)5 * 64 * 64 * 4);
    float* x_d0c = (float*)alloc((size_t)16 * 5 * 4 * 4);
    float* p_d1g = (float*)alloc((size_t)5 * 128 * 128 * 4);
    float* p_d1c = (float*)alloc((size_t)5 * 128 * 64 * 4);
    float* xdum  = (float*)alloc((size_t)16 * 5 * 8 * 4);
    if (off > ws_size) return;

    {
        int nz = CAP * 1024 * 4;  // ell8 + ell4 as ints (contiguous)
        zero_kernel<<<(nz + 255) / 256, 256, 0, stream>>>((float*)ell8, nz);
    }
    row_counts<<<256, 256, 0, stream>>>(supports, cnt);
    perm_build<<<1, 512, 0, stream>>>(cnt, nmap, rankv);
    build_ell<<<256, 256, 0, stream>>>(supports, nmap, rankv, ell8, ell4, ecnt);
    wmax_kernel<<<1, 16, 0, stream>>>(ecnt, wmax);
    {
        int nz = RTOT * UU * 2 + RTOT;  // h0a, h1a, xzero contiguous
        zero_kernel<<<(nz + 255) / 256, 256, 0, stream>>>(h0a, nz);
    }
    wprep<<<(5 * 64 * 128 + 255) / 256, 256, 0, stream>>>(enc0_Wg, p_e0g, x_e0g, 64, 128, 8, 1);
    wprep<<<(5 * 64 * 64 + 255) / 256, 256, 0, stream>>>(enc0_Wc, p_e0c, x_e0c, 64, 64, 4, 1);
    wprep<<<(5 * 128 * 128 + 255) / 256, 256, 0, stream>>>(enc1_Wg, p_e1g, xdum, 128, 128, 8, 0);
    wprep<<<(5 * 128 * 64 + 255) / 256, 256, 0, stream>>>(enc1_Wc, p_e1c, xdum, 128, 64, 4, 0);
    wprep<<<(5 * 64 * 128 + 255) / 256, 256, 0, stream>>>(dec0_Wg, p_d0g, x_d0g, 64, 128, 8, 1);
    wprep<<<(5 * 64 * 64 + 255) / 256, 256, 0, stream>>>(dec0_Wc, p_d0c, x_d0c, 64, 64, 4, 1);
    wprep<<<(5 * 128 * 128 + 255) / 256, 256, 0, stream>>>(dec1_Wg, p_d1g, xdum, 128, 128, 8, 0);
    wprep<<<(5 * 128 * 64 + 255) / 256, 256, 0, stream>>>(dec1_Wc, p_d1c, xdum, 128, 64, 4, 0);

    float *h0c = h0a, *h0n = h0b, *h1c = h1a, *h1n = h1b;

    auto cell_l0 = [&](const float* x_bn, const float* Wg_, const float* Xg_,
                       const float* bg_, const float* Wc_, const float* Xc_,
                       const float* bc_) {
        fused<true, true><<<512, 512, 0, stream>>>(h0c, nullptr, g0, Wg_, Xg_, x_bn, nmap,
                                                   bg_, ell8, wmax, g0, nullptr, nullptr);
        fused<true, false><<<512, 512, 0, stream>>>(h0c, nullptr, g0, Wc_, Xc_, x_bn, nmap,
                                                    bc_, ell4, wmax, nullptr, h0c, h0n);
        float* t = h0c; h0c = h0n; h0n = t;
    };
    // paired: A = enc l1 (uses h0c,h1c -> h1n), B = l0-type cell (xB, weights) -> h0n
    auto pair_step = [&](const float* xB, const float* BWg, const float* BXg,
                         const float* Bbg, const float* BWc, const float* BXc,
                         const float* Bbc) {
        fused_pair<true><<<1024, 512, 0, stream>>>(
            nmap, ell8, wmax,
            h0c, h1c, g1, p_e1g, enc1_bg, g1, nullptr, nullptr,
            h0c, g0, BWg, BXg, xB, Bbg, g0, nullptr, nullptr);
        fused_pair<false><<<1024, 512, 0, stream>>>(
            nmap, ell4, wmax,
            h0c, h1c, g1, p_e1c, enc1_bc, nullptr, h1c, h1n,
            h0c, g0, BWc, BXc, xB, Bbc, nullptr, h0c, h0n);
        float* t = h0c; h0c = h0n; h0n = t;
        t = h1c; h1c = h1n; h1n = t;
    };

    // ---- encoder with cross-cell pairing ----
    cell_l0(inputs, p_e0g, x_e0g, enc0_bg, p_e0c, x_e0c, enc0_bc);      // l0(0)
    for (int t = 1; t < TT; ++t)                                        // {l1(t-1) || l0(t)}
        pair_step(inputs + (size_t)t * BB * NN,
                  p_e0g, x_e0g, enc0_bg, p_e0c, x_e0c, enc0_bc);
    // bridge: {enc l1(11) || dec l0(0) with x = 0}
    pair_step(xzero, p_d0g, x_d0g, dec0_bg, p_d0c, x_d0c, dec0_bc);

    // ---- decoder (serial: out(t) feeds l0(t+1)) ----
    auto cell_l1_dec = [&]() {
        fused<false, true><<<512, 512, 0, stream>>>(h0c, h1c, g1, p_d1g, nullptr, nullptr, nmap,
                                                    dec1_bg, ell8, wmax, g1, nullptr, nullptr);
        fused<false, false><<<512, 512, 0, stream>>>(h0c, h1c, g1, p_d1c, nullptr, nullptr, nmap,
                                                     dec1_bc, ell4, wmax, nullptr, h1c, h1n);
        float* t = h1c; h1c = h1n; h1n = t;
    };

    cell_l1_dec();
    proj_kernel<<<(RTOT + 255) / 256, 256, 0, stream>>>(h1c, projW, projb, nmap, out);
    for (int t = 1; t < HH; ++t) {
        const float* xin = out + (size_t)(t - 1) * BB * NN;
        cell_l0(xin, p_d0g, x_d0g, dec0_bg, p_d0c, x_d0c, dec0_bc);
        cell_l1_dec();
        proj_kernel<<<(RTOT + 255) / 256, 256, 0, stream>>>(h1c, projW, projb, nmap,
                                                            out + (size_t)t * BB * NN);
    }
}

// Round 22
// 4538.493 us; speedup vs baseline: 1.0814x; 1.0210x over previous
//
#include <hip/hip_runtime.h>
#include <math.h>

#define NN 512
#define BB 32
#define TT 12
#define HH 12
#define UU 64
#define CAP 128
#define RTOT (NN * BB)          // 16384 rows

__device__ __forceinline__ float sigm(float x) { return 1.f / (1.f + expf(-x)); }

__global__ void zero_kernel(float* __restrict__ p, int n) {
    int i = blockIdx.x * 256 + threadIdx.x;
    if (i < n) p[i] = 0.0f;
}

// ---------------- per-row nonzero counts (wave per row, both supports) ----------
__global__ __launch_bounds__(256) void row_counts(const float* __restrict__ sup,
                                                  int* __restrict__ cnt) {
    int wave = (blockIdx.x * 256 + threadIdx.x) >> 6;
    int lane = threadIdx.x & 63;
    if (wave >= 2 * NN) return;
    const float* row = sup + (size_t)wave * NN;
    int c = 0;
    for (int k = 0; k < 8; ++k)
        c += __popcll(__ballot(row[k * 64 + lane] != 0.0f));
    if (lane == 0) cnt[wave] = c;
}

// ---------------- degree-sort permutation (deterministic counting sort) ---------
__global__ __launch_bounds__(512) void perm_build(const int* __restrict__ cnt,
                                                  int* __restrict__ nmap,
                                                  int* __restrict__ rankv) {
    __shared__ int hist[520];
    __shared__ int keys[512];
    int n = threadIdx.x;
    int c0 = cnt[n], c1 = cnt[NN + n];
    int key = c0 > c1 ? c0 : c1;
    hist[n] = 0;
    if (n < 8) hist[512 + n] = 0;
    __syncthreads();
    keys[n] = key;
    atomicAdd(&hist[key], 1);
    __syncthreads();
    if (n == 0) {
        int s = 0;
        for (int i = 0; i < 520; ++i) { int h = hist[i]; hist[i] = s; s += h; }
    }
    __syncthreads();
    int pos = hist[key];
    for (int i = 0; i < n; ++i)
        if (keys[i] == key) ++pos;
    nmap[pos] = n;
    rankv[n] = pos;
}

// ---------------- ELL build in permuted node space, pre-baked LDS offsets -------
__global__ __launch_bounds__(256) void build_ell(const float* __restrict__ sup,
                                                 const int* __restrict__ nmap,
                                                 const int* __restrict__ rankv,
                                                 int2* __restrict__ ell8,
                                                 int2* __restrict__ ell4,
                                                 int* __restrict__ ecnt) {
    int wave = (blockIdx.x * blockDim.x + threadIdx.x) >> 6;
    int lane = threadIdx.x & 63;
    if (wave >= 2 * NN) return;
    int s = wave >> 9, rp = wave & 511;
    const float* row = sup + ((size_t)s * NN + nmap[rp]) * NN;
    int base = 0;
    for (int k = 0; k < NN / 64; ++k) {
        float v = row[k * 64 + lane];
        unsigned long long m = __ballot(v != 0.0f);
        int pre = __popcll(m & ((1ull << lane) - 1ull));
        if (v != 0.0f) {
            int pos = base + pre;
            if (pos < CAP) {
                int j = rankv[k * 64 + lane];
                int vb = __float_as_int(v);
                ell8[(size_t)pos * 1024 + wave] = make_int2(j * 32 + ((j >> 2) & 1) * 16, vb);
                ell4[(size_t)pos * 1024 + wave] = make_int2(j * 16, vb);
            }
        }
        base += __popcll(m);
    }
    if (lane == 0) ecnt[wave] = base < CAP ? base : CAP;
}

__global__ void wmax_kernel(const int* __restrict__ ecnt, int* __restrict__ wmax) {
    int g = threadIdx.x;
    if (g >= 16) return;
    int s = g >> 3, grp = g & 7;
    int m = 0;
    for (int i = 0; i < 64; ++i) {
        int c = ecnt[s * NN + grp * 64 + i];
        m = c > m ? c : m;
    }
    wmax[g] = m;
}

// ---------------- weight prep: permute to [oq][m][c][WD] + x-row table ----------
__global__ void wprep(const float* __restrict__ src, float* __restrict__ dstP,
                      float* __restrict__ dstX, int C, int OO, int WD, int L0) {
    int idx = blockIdx.x * 256 + threadIdx.x;
    int total = 5 * C * OO;
    if (idx >= total) return;
    int oi = idx % WD;
    int rem = idx / WD;
    int c = rem % C;
    int rem2 = rem / C;
    int m = rem2 % 5;
    int oq = rem2 / 5;
    int o = oq * WD + oi;
    int crow = L0 ? (c + 1) : c;
    size_t base = (size_t)crow * 5 * OO + o;
    float v;
    if (m == 0) v = src[base] - src[base + 2 * OO] - src[base + 4 * OO];
    else        v = src[base + (size_t)m * OO];
    dstP[idx] = v;
    if (L0 && c == 0) {
        size_t b0 = (size_t)o;
        float xvv;
        if (m == 0) xvv = src[b0] - src[b0 + 2 * OO] - src[b0 + 4 * OO];
        else        xvv = src[b0 + (size_t)m * OO];
        dstX[(oq * 5 + m) * WD + oi] = xvv;
    }
}

// ---------------- fused gconv body ----------------------------------------------
// P1 c-loop manually 4-wide batched: 4 independent A loads issued back-to-back
// before the FMA blocks (MLP for the latency-bound global loads). Per-accumulator
// fp order unchanged (c ascending) -> bitwise-identical output.
template<bool L0, bool GATE>
__device__ __forceinline__ void fused_body(int bid, float* __restrict__ S,
                                           const float* __restrict__ hA,
                                           const float* __restrict__ hB,
                                           const float* __restrict__ g,
                                           const float* __restrict__ Wp,
                                           const float* __restrict__ Xr,
                                           const float* __restrict__ xv,
                                           const int* __restrict__ nmap,
                                           const float* __restrict__ bias,
                                           const int2* __restrict__ ell,
                                           const int* __restrict__ wmax,
                                           float* __restrict__ gout,
                                           const float* __restrict__ hOld,
                                           float* __restrict__ hNew) {
    constexpr int C  = L0 ? 64 : 128;
    constexpr int WD = GATE ? 8 : 4;

    float* T0 = S;
    float* T1 = S + 512 * WD;

    int swz = (bid & 7) * 64 + (bid >> 3);  // XCD-contiguous (512 sub-blocks)
    int b = swz >> 4, oq = swz & 15;
    int o0 = oq * WD;
    int n = threadIdx.x;
    int wm0 = wmax[n >> 6];
    int wm1 = wmax[8 + (n >> 6)];
    float xn = L0 ? xv[b * 512 + nmap[n]] : 0.f;

    const float* Wb = Wp + (size_t)oq * 5 * C * WD;
    float acc[5][WD];
    #pragma unroll
    for (int oi = 0; oi < WD; ++oi) acc[0][oi] = bias[o0 + oi];
    #pragma unroll
    for (int m = 1; m < 5; ++m)
        #pragma unroll
        for (int oi = 0; oi < WD; ++oi) acc[m][oi] = 0.f;

    auto loadA = [&](int c) -> float {
        if (L0) {
            if (GATE) return hA[(size_t)((b << 6) + c) * 512 + n];
            else      return g[(size_t)((b << 7) + c) * 512 + n];      // rh
        } else {
            if (c < 64) return hA[(size_t)((b << 6) + c) * 512 + n];
            int u = c - 64;
            if (GATE) return hB[(size_t)((b << 6) + u) * 512 + n];
            else      return g[(size_t)((b << 7) + u) * 512 + n];      // rh
        }
    };

    for (int c0 = 0; c0 < C; c0 += 4) {
        float a0 = loadA(c0);
        float a1 = loadA(c0 + 1);
        float a2 = loadA(c0 + 2);
        float a3 = loadA(c0 + 3);
        #pragma unroll
        for (int m = 0; m < 5; ++m) {
            const float* w0 = Wb + ((size_t)m * C + c0) * WD;
            #pragma unroll
            for (int oi = 0; oi < WD; ++oi) acc[m][oi] += a0 * w0[oi];
        }
        #pragma unroll
        for (int m = 0; m < 5; ++m) {
            const float* w1 = Wb + ((size_t)m * C + c0 + 1) * WD;
            #pragma unroll
            for (int oi = 0; oi < WD; ++oi) acc[m][oi] += a1 * w1[oi];
        }
        #pragma unroll
        for (int m = 0; m < 5; ++m) {
            const float* w2 = Wb + ((size_t)m * C + c0 + 2) * WD;
            #pragma unroll
            for (int oi = 0; oi < WD; ++oi) acc[m][oi] += a2 * w2[oi];
        }
        #pragma unroll
        for (int m = 0; m < 5; ++m) {
            const float* w3 = Wb + ((size_t)m * C + c0 + 3) * WD;
            #pragma unroll
            for (int oi = 0; oi < WD; ++oi) acc[m][oi] += a3 * w3[oi];
        }
    }

    if (L0) {
        const float* xr = Xr + (size_t)oq * 5 * WD;
        #pragma unroll
        for (int m = 0; m < 5; ++m)
            #pragma unroll
            for (int oi = 0; oi < WD; ++oi)
                acc[m][oi] += xn * xr[m * WD + oi];
    }

    float uval[WD], hval[WD];
    if (!GATE) {
        #pragma unroll
        for (int oi = 0; oi < WD; ++oi) {
            uval[oi] = g[(size_t)((b << 7) + 64 + o0 + oi) * 512 + n];
            hval[oi] = hOld[(size_t)((b << 6) + o0 + oi) * 512 + n];
        }
    }

    int hsel = (n >> 2) & 1;
    if constexpr (WD == 8) {
        *(float4*)&T0[n * 8 + hsel * 4] =
            make_float4(acc[2][0], acc[2][1], acc[2][2], acc[2][3]);
        *(float4*)&T0[n * 8 + (hsel ^ 1) * 4] =
            make_float4(acc[2][4], acc[2][5], acc[2][6], acc[2][7]);
        *(float4*)&T1[n * 8 + hsel * 4] =
            make_float4(acc[4][0], acc[4][1], acc[4][2], acc[4][3]);
        *(float4*)&T1[n * 8 + (hsel ^ 1) * 4] =
            make_float4(acc[4][4], acc[4][5], acc[4][6], acc[4][7]);
    } else {
        *(float4*)&T0[n * 4] = make_float4(acc[2][0], acc[2][1], acc[2][2], acc[2][3]);
        *(float4*)&T1[n * 4] = make_float4(acc[4][0], acc[4][1], acc[4][2], acc[4][3]);
    }

    auto gather = [&](const float* T, const int2* e0, int wm, float* o) {
        const char* Tbyte = (const char*)T;
        float a0[WD];
        #pragma unroll
        for (int i = 0; i < WD; ++i) a0[i] = 0.f;
        #pragma unroll 4
        for (int p = 0; p < wm; ++p) {
            int2 e = e0[(size_t)p << 10];
            float v = __int_as_float(e.y);
            if constexpr (WD == 8) {
                float4 x0 = *(const float4*)(Tbyte + e.x);
                float4 x1 = *(const float4*)(Tbyte + (e.x ^ 16));
                a0[0] += v * x0.x; a0[1] += v * x0.y; a0[2] += v * x0.z; a0[3] += v * x0.w;
                a0[4] += v * x1.x; a0[5] += v * x1.y; a0[6] += v * x1.z; a0[7] += v * x1.w;
            } else {
                float4 x0 = *(const float4*)(Tbyte + e.x);
                a0[0] += v * x0.x; a0[1] += v * x0.y; a0[2] += v * x0.z; a0[3] += v * x0.w;
            }
        }
        #pragma unroll
        for (int i = 0; i < WD; ++i) o[i] = a0[i];
    };
    auto put = [&](float* T, const float* y) {
        if constexpr (WD == 8) {
            *(float4*)&T[n * 8 + hsel * 4]       = make_float4(y[0], y[1], y[2], y[3]);
            *(float4*)&T[n * 8 + (hsel ^ 1) * 4] = make_float4(y[4], y[5], y[6], y[7]);
        } else {
            *(float4*)&T[n * 4] = make_float4(y[0], y[1], y[2], y[3]);
        }
    };

    const int2* e00 = ell + n;
    const int2* e01 = ell + NN + n;
    float g2[WD], g4[WD], t1[WD];

    __syncthreads();                    // bar 1: T0/T1 staged

    gather(T0, e00, wm0, t1);           // S1 Z2
    #pragma unroll
    for (int oi = 0; oi < WD; ++oi) acc[1][oi] += 2.f * t1[oi];
    gather(T1, e01, wm1, t1);           // S2 Z4
    #pragma unroll
    for (int oi = 0; oi < WD; ++oi) acc[3][oi] += 2.f * t1[oi];

    __syncthreads();                    // bar 2: hop-1 reads done

    put(T0, acc[1]);
    put(T1, acc[3]);

    __syncthreads();                    // bar 3: y tiles ready

    gather(T0, e00, wm0, g2);           // S1 y1
    gather(T1, e01, wm1, g4);           // S2 y2

    #pragma unroll
    for (int oi = 0; oi < WD; ++oi) {
        float accf = acc[0][oi] + g2[oi] + g4[oi];
        if (GATE) {
            float s = sigm(accf);
            if (oq < 8) {               // r-half: write rh = r * h (rh-fusion)
                const float* hG = L0 ? hA : hB;
                float hv = hG[(size_t)((b << 6) + o0 + oi) * 512 + n];
                gout[(size_t)((b << 7) + o0 + oi) * 512 + n] = s * hv;
            } else {
                gout[(size_t)((b << 7) + o0 + oi) * 512 + n] = s;
            }
        } else {
            float cv = tanhf(accf);
            hNew[(size_t)((b << 6) + o0 + oi) * 512 + n] =
                uval[oi] * hval[oi] + (1.f - uval[oi]) * cv;
        }
    }
}

// ---------------- standalone kernel ---------------------------------------------
template<bool L0, bool GATE>
__global__ __launch_bounds__(512) void fused(const float* __restrict__ hA,
                                             const float* __restrict__ hB,
                                             const float* __restrict__ g,
                                             const float* __restrict__ Wp,
                                             const float* __restrict__ Xr,
                                             const float* __restrict__ xv,
                                             const int* __restrict__ nmap,
                                             const float* __restrict__ bias,
                                             const int2* __restrict__ ell,
                                             const int* __restrict__ wmax,
                                             float* __restrict__ gout,
                                             const float* __restrict__ hOld,
                                             float* __restrict__ hNew) {
    __shared__ float S[512 * (GATE ? 8 : 4) * 2];
    fused_body<L0, GATE>(blockIdx.x, S, hA, hB, g, Wp, Xr, xv, nmap, bias,
                         ell, wmax, gout, hOld, hNew);
}

// ---------------- paired kernel (A/B interleave across CUs) ---------------------
template<bool GATE>
__global__ __launch_bounds__(512) void fused_pair(
        const int* __restrict__ nmap, const int2* __restrict__ ell,
        const int* __restrict__ wmax,
        const float* __restrict__ AhA, const float* __restrict__ AhB,
        const float* __restrict__ Ag,  const float* __restrict__ AWp,
        const float* __restrict__ Abias, float* __restrict__ Agout,
        const float* __restrict__ AhOld, float* __restrict__ AhNew,
        const float* __restrict__ BhA, const float* __restrict__ Bg,
        const float* __restrict__ BWp, const float* __restrict__ BXr,
        const float* __restrict__ Bxv, const float* __restrict__ Bbias,
        float* __restrict__ Bgout, const float* __restrict__ BhOld,
        float* __restrict__ BhNew) {
    __shared__ float S[512 * (GATE ? 8 : 4) * 2];
    int chunk = blockIdx.x >> 8;
    int unit = chunk & 1;
    int sub = ((chunk >> 1) << 8) + (blockIdx.x & 255);
    if (unit == 0)
        fused_body<false, GATE>(sub, S, AhA, AhB, Ag, AWp, nullptr, nullptr,
                                nmap, Abias, ell, wmax, Agout, AhOld, AhNew);
    else
        fused_body<true, GATE>(sub, S, BhA, nullptr, Bg, BWp, BXr, Bxv,
                               nmap, Bbias, ell, wmax, Bgout, BhOld, BhNew);
}

// ---------------- projection (write through nmap to original node order) --------
__global__ void proj_kernel(const float* __restrict__ h1, const float* __restrict__ pW,
                            const float* __restrict__ pb, const int* __restrict__ nmap,
                            float* __restrict__ outt) {
    int r = blockIdx.x * 256 + threadIdx.x;
    if (r >= RTOT) return;
    int b = r >> 9, n = r & 511;
    float acc = pb[0];
    #pragma unroll 16
    for (int u = 0; u < 64; ++u)
        acc += h1[(size_t)((b << 6) + u) * 512 + n] * pW[u];
    outt[b * NN + nmap[n]] = acc;
}

// ================================================================================
extern "C" void kernel_launch(void* const* d_in, const int* in_sizes, int n_in,
                              void* d_out, int out_size, void* d_ws, size_t ws_size,
                              hipStream_t stream) {
    const float* inputs   = (const float*)d_in[0];
    const float* supports = (const float*)d_in[1];
    const float* enc0_Wg = (const float*)d_in[2];
    const float* enc0_bg = (const float*)d_in[3];
    const float* enc0_Wc = (const float*)d_in[4];
    const float* enc0_bc = (const float*)d_in[5];
    const float* enc1_Wg = (const float*)d_in[6];
    const float* enc1_bg = (const float*)d_in[7];
    const float* enc1_Wc = (const float*)d_in[8];
    const float* enc1_bc = (const float*)d_in[9];
    const float* dec0_Wg = (const float*)d_in[10];
    const float* dec0_bg = (const float*)d_in[11];
    const float* dec0_Wc = (const float*)d_in[12];
    const float* dec0_bc = (const float*)d_in[13];
    const float* dec1_Wg = (const float*)d_in[14];
    const float* dec1_bg = (const float*)d_in[15];
    const float* dec1_Wc = (const float*)d_in[16];
    const float* dec1_bc = (const float*)d_in[17];
    const float* projW   = (const float*)d_in[18];
    const float* projb   = (const float*)d_in[19];
    float* out = (float*)d_out;

    char* wsb = (char*)d_ws;
    size_t off = 0;
    auto alloc = [&](size_t bytes) -> char* {
        char* p = wsb + off;
        off = (off + bytes + 255) & ~(size_t)255;
        return p;
    };
    int2*  ell8  = (int2*)alloc((size_t)CAP * 1024 * 8);
    int2*  ell4  = (int2*)alloc((size_t)CAP * 1024 * 8);
    int*   cnt   = (int*)alloc((size_t)2 * NN * 4);
    int*   nmap  = (int*)alloc((size_t)NN * 4);
    int*   rankv = (int*)alloc((size_t)NN * 4);
    int*   ecnt  = (int*)alloc((size_t)2 * NN * 4);
    int*   wmax  = (int*)alloc((size_t)16 * 4);
    float* h0a   = (float*)alloc((size_t)RTOT * UU * 4);     // [b][u][n]
    float* h1a   = (float*)alloc((size_t)RTOT * UU * 4);
    float* xzero = (float*)alloc((size_t)RTOT * 4);
    float* h0b   = (float*)alloc((size_t)RTOT * UU * 4);
    float* h1b   = (float*)alloc((size_t)RTOT * UU * 4);
    float* g0    = (float*)alloc((size_t)RTOT * 128 * 4);
    float* g1    = (float*)alloc((size_t)RTOT * 128 * 4);
    float* p_e0g = (float*)alloc((size_t)5 * 64 * 128 * 4);
    float* x_e0g = (float*)alloc((size_t)16 * 5 * 8 * 4);
    float* p_e0c = (float*)alloc((size_t)5 * 64 * 64 * 4);
    float* x_e0c = (float*)alloc((size_t)16 * 5 * 4 * 4);
    float* p_e1g = (float*)alloc((size_t)5 * 128 * 128 * 4);
    float* p_e1c = (float*)alloc((size_t)5 * 128 * 64 * 4);
    float* p_d0g = (float*)alloc((size_t)5 * 64 * 128 * 4);
    float* x_d0g = (float*)alloc((size_t)16 * 5 * 8 * 4);
    float* p_d0c = (float*)alloc((size_t)5 * 64 * 64 * 4);
    float* x_d0c = (float*)alloc((size_t)16 * 5 * 4 * 4);
    float* p_d1g = (float*)alloc((size_t)5 * 128 * 128 * 4);
    float* p_d1c = (float*)alloc((size_t)5 * 128 * 64 * 4);
    float* xdum  = (float*)alloc((size_t)16 * 5 * 8 * 4);
    if (off > ws_size) return;

    {
        int nz = CAP * 1024 * 4;  // ell8 + ell4 as ints (contiguous)
        zero_kernel<<<(nz + 255) / 256, 256, 0, stream>>>((float*)ell8, nz);
    }
    row_counts<<<256, 256, 0, stream>>>(supports, cnt);
    perm_build<<<1, 512, 0, stream>>>(cnt, nmap, rankv);
    build_ell<<<256, 256, 0, stream>>>(supports, nmap, rankv, ell8, ell4, ecnt);
    wmax_kernel<<<1, 16, 0, stream>>>(ecnt, wmax);
    {
        int nz = RTOT * UU * 2 + RTOT;  // h0a, h1a, xzero contiguous
        zero_kernel<<<(nz + 255) / 256, 256, 0, stream>>>(h0a, nz);
    }
    wprep<<<(5 * 64 * 128 + 255) / 256, 256, 0, stream>>>(enc0_Wg, p_e0g, x_e0g, 64, 128, 8, 1);
    wprep<<<(5 * 64 * 64 + 255) / 256, 256, 0, stream>>>(enc0_Wc, p_e0c, x_e0c, 64, 64, 4, 1);
    wprep<<<(5 * 128 * 128 + 255) / 256, 256, 0, stream>>>(enc1_Wg, p_e1g, xdum, 128, 128, 8, 0);
    wprep<<<(5 * 128 * 64 + 255) / 256, 256, 0, stream>>>(enc1_Wc, p_e1c, xdum, 128, 64, 4, 0);
    wprep<<<(5 * 64 * 128 + 255) / 256, 256, 0, stream>>>(dec0_Wg, p_d0g, x_d0g, 64, 128, 8, 1);
    wprep<<<(5 * 64 * 64 + 255) / 256, 256, 0, stream>>>(dec0_Wc, p_d0c, x_d0c, 64, 64, 4, 1);
    wprep<<<(5 * 128 * 128 + 255) / 256, 256, 0, stream>>>(dec1_Wg, p_d1g, xdum, 128, 128, 8, 0);
    wprep<<<(5 * 128 * 64 + 255) / 256, 256, 0, stream>>>(dec1_Wc, p_d1c, xdum, 128, 64, 4, 0);

    float *h0c = h0a, *h0n = h0b, *h1c = h1a, *h1n = h1b;

    auto cell_l0 = [&](const float* x_bn, const float* Wg_, const float* Xg_,
                       const float* bg_, const float* Wc_, const float* Xc_,
                       const float* bc_) {
        fused<true, true><<<512, 512, 0, stream>>>(h0c, nullptr, g0, Wg_, Xg_, x_bn, nmap,
                                                   bg_, ell8, wmax, g0, nullptr, nullptr);
        fused<true, false><<<512, 512, 0, stream>>>(h0c, nullptr, g0, Wc_, Xc_, x_bn, nmap,
                                                    bc_, ell4, wmax, nullptr, h0c, h0n);
        float* t = h0c; h0c = h0n; h0n = t;
    };
    auto pair_step = [&](const float* xB, const float* BWg, const float* BXg,
                         const float* Bbg, const float* BWc, const float* BXc,
                         const float* Bbc) {
        fused_pair<true><<<1024, 512, 0, stream>>>(
            nmap, ell8, wmax,
            h0c, h1c, g1, p_e1g, enc1_bg, g1, nullptr, nullptr,
            h0c, g0, BWg, BXg, xB, Bbg, g0, nullptr, nullptr);
        fused_pair<false><<<1024, 512, 0, stream>>>(
            nmap, ell4, wmax,
            h0c, h1c, g1, p_e1c, enc1_bc, nullptr, h1c, h1n,
            h0c, g0, BWc, BXc, xB, Bbc, nullptr, h0c, h0n);
        float* t = h0c; h0c = h0n; h0n = t;
        t = h1c; h1c = h1n; h1n = t;
    };

    // ---- encoder with cross-cell pairing ----
    cell_l0(inputs, p_e0g, x_e0g, enc0_bg, p_e0c, x_e0c, enc0_bc);      // l0(0)
    for (int t = 1; t < TT; ++t)                                        // {l1(t-1) || l0(t)}
        pair_step(inputs + (size_t)t * BB * NN,
                  p_e0g, x_e0g, enc0_bg, p_e0c, x_e0c, enc0_bc);
    // bridge: {enc l1(11) || dec l0(0) with x = 0}
    pair_step(xzero, p_d0g, x_d0g, dec0_bg, p_d0c, x_d0c, dec0_bc);

    // ---- decoder (serial: out(t) feeds l0(t+1)) ----
    auto cell_l1_dec = [&]() {
        fused<false, true><<<512, 512, 0, stream>>>(h0c, h1c, g1, p_d1g, nullptr, nullptr, nmap,
                                                    dec1_bg, ell8, wmax, g1, nullptr, nullptr);
        fused<false, false><<<512, 512, 0, stream>>>(h0c, h1c, g1, p_d1c, nullptr, nullptr, nmap,
                                                     dec1_bc, ell4, wmax, nullptr, h1c, h1n);
        float* t = h1c; h1c = h1n; h1n = t;
    };

    cell_l1_dec();
    proj_kernel<<<(RTOT + 255) / 256, 256, 0, stream>>>(h1c, projW, projb, nmap, out);
    for (int t = 1; t < HH; ++t) {
        const float* xin = out + (size_t)(t - 1) * BB * NN;
        cell_l0(xin, p_d0g, x_d0g, dec0_bg, p_d0c, x_d0c, dec0_bc);
        cell_l1_dec();
        proj_kernel<<<(RTOT + 255) / 256, 256, 0, stream>>>(h1c, projW, projb, nmap,
                                                            out + (size_t)t * BB * NN);
    }
}